// Round 5
// baseline (127.078 us; speedup 1.0000x reference)
//
#include <hip/hip_runtime.h>
#include <cstdint>
#include <cstring>

#define BATCH   4096
#define DIM     128
#define NLAYERS 8
#define KNODES  8
#define NDEG    4
#define NNODES  65
#define NODE_ELEMS (BATCH * DIM)   // 524288 elems
#define ROWS    16                  // rows per block tile
#define SLOTS   37                  // LDS-resident activation slots
#define TILE_B  (ROWS * 256)        // 4096 B per bf16 tile (16 rows x 128 cols)
#define NTHREADS 1024

typedef float    f32x4 __attribute__((ext_vector_type(4)));
typedef short    s16x8 __attribute__((ext_vector_type(8)));
typedef uint32_t u32x4 __attribute__((ext_vector_type(4)));

struct LayerSrcs { int p[KNODES][NDEG]; };

struct Sched {
  uint64_t pinfo[NLAYERS * KNODES];  // per node: 4 x {slot+1 (8b), src node id (8b)}
  int8_t   dst[NLAYERS * KNODES];    // >=0 LDS slot, -1 global spill, -2 mean-only, -3 dead
  int8_t   root_dst;
};

// ---------------- device helpers ----------------
__device__ __forceinline__ uint32_t f2bf(float f) {   // RNE round to bf16
  union { float f; uint32_t i; } x; x.f = f;
  return (x.i + 0x7fffu + ((x.i >> 16) & 1u)) >> 16;
}
__device__ __forceinline__ uint32_t pack2(float a, float b) {
  return f2bf(a) | (f2bf(b) << 16);
}

// ---------------- W pre-pack: f32 row-major -> bf16 MFMA-fragment-linear ----------------
// chunk ci = (node*4 + ks)*8 + panel; elem offset = ci*512 + lane*8.
// element e = W[node][col = panel*16 + (lane&15)][k = ks*32 + (lane>>4)*8 + e]
__global__ __launch_bounds__(256)
void pack_w(const float* __restrict__ W, uint16_t* __restrict__ Wp) {
  int gid  = blockIdx.x * 256 + threadIdx.x;     // 65*2048 = 133120 total
  int lane = gid & 63;
  int n    = (gid >> 6) & 7;
  int ks   = (gid >> 9) & 3;
  int node = gid >> 11;
  int col  = n * 16 + (lane & 15);
  int k0   = ks * 32 + (lane >> 4) * 8;
  const float* src = W + ((size_t)node * DIM + col) * DIM + k0;
  f32x4 v0 = *(const f32x4*)src;
  f32x4 v1 = *(const f32x4*)(src + 4);
  u32x4 pk;
  pk.x = pack2(v0.x, v0.y); pk.y = pack2(v0.z, v0.w);
  pk.z = pack2(v1.x, v1.y); pk.w = pack2(v1.z, v1.w);
  *(u32x4*)(Wp + (size_t)gid * 8) = pk;
}

// ---------------- the persistent DAG executor ----------------
// 1024 threads = 16 waves = 8 nodes x 2 col-halves. One barrier per layer.
// Parent sum folded into the MFMA accumulator; W fragments register-prefetched
// in two batches of 8 so >=8 L2 loads are in flight (latency-bound fix, R4->R5).
__global__ __launch_bounds__(NTHREADS)
void dag_exec(const float* __restrict__ X, const uint16_t* __restrict__ Wp,
              const float* __restrict__ bias, uint16_t* __restrict__ outs,
              float* __restrict__ out, Sched sch)
{
  __shared__ char lds[SLOTS * TILE_B + 2048 * 4];   // 37 slots + f32 mean buffer = 156 KB
  float* mb = (float*)(lds + (size_t)SLOTS * TILE_B);

  const int t    = threadIdx.x;
  const int lane = t & 63;
  const int wv   = t >> 6;
  const int lr   = lane & 15;
  const int lg   = lane >> 4;
  const int kn   = wv & 7;      // node within layer
  const int h    = wv >> 3;     // col half (64 cols)
  const int row0 = blockIdx.x * ROWS;

  mb[t] = 0.f;
  mb[t + 1024] = 0.f;

  // ---- root: node 0, A = bf16(X); 8 waves, one col-panel each ----
  if (wv < 8) {
    f32x4 acc = (f32x4){0.f, 0.f, 0.f, 0.f};
    // prefetch the 4 W fragments for this panel
    s16x8 wf[4];
#pragma unroll
    for (int ks = 0; ks < 4; ++ks)
      wf[ks] = *(const s16x8*)(Wp + (((size_t)(0 * 4 + ks) * 8 + wv) << 9) + lane * 8);
#pragma unroll
    for (int ks = 0; ks < 4; ++ks) {
      const float* xp = X + (size_t)(row0 + lr) * DIM + ks * 32 + lg * 8;
      f32x4 v0 = *(const f32x4*)xp;
      f32x4 v1 = *(const f32x4*)(xp + 4);
      u32x4 pk;
      pk.x = pack2(v0.x, v0.y); pk.y = pack2(v0.z, v0.w);
      pk.z = pack2(v1.x, v1.y); pk.w = pack2(v1.z, v1.w);
      s16x8 af;
      __builtin_memcpy(&af, &pk, 16);
      acc = __builtin_amdgcn_mfma_f32_16x16x32_bf16(af, wf[ks], acc, 0, 0, 0);
    }
    char* db = lds + (size_t)sch.root_dst * TILE_B;
    const int col = wv * 16 + lr;
    const float bv = bias[col];
#pragma unroll
    for (int j = 0; j < 4; ++j) {
      const int row = lg * 4 + j;
      float v = fmaxf(acc[j] + bv, 0.f);
      *(uint16_t*)(db + ((row * 256 + col * 2) ^ ((row & 7) << 4))) = (uint16_t)f2bf(v);
    }
  }
  __syncthreads();

  // ---- 8 layers, one wave-task per (node, col-half), one barrier per layer ----
  for (int l = 0; l < NLAYERS; ++l) {
    const int idx  = l * KNODES + kn;
    const int node = 1 + idx;
    const int dv   = sch.dst[idx];
    const uint64_t pinfo = sch.pinfo[idx];

    if (dv != -3) {
      // --- prefetch batch 1: W fragments for ks 0..1 (8 loads) + bias ---
      s16x8 wf[4][4];
#pragma unroll
      for (int ks = 0; ks < 2; ++ks)
#pragma unroll
        for (int n = 0; n < 4; ++n)
          wf[ks][n] = *(const s16x8*)(Wp +
              ((((size_t)node * 4 + ks) * 8 + h * 4 + n) << 9) + lane * 8);
      float bv[4];
#pragma unroll
      for (int n = 0; n < 4; ++n)
        bv[n] = bias[(size_t)node * DIM + (h * 4 + n) * 16 + lr];

      f32x4 acc[4];
#pragma unroll
      for (int n = 0; n < 4; ++n) acc[n] = (f32x4){0.f, 0.f, 0.f, 0.f};

#pragma unroll
      for (int ks = 0; ks < 4; ++ks) {
        s16x8 af[NDEG];
#pragma unroll
        for (int p = 0; p < NDEG; ++p) {
          const int e  = (int)((pinfo >> (p * 16)) & 0xffff);
          const int ps = (e & 0xff) - 1;
          if (ps >= 0) {
            af[p] = *(const s16x8*)(lds + (size_t)ps * TILE_B +
                     ((lr * 256 + ks * 64 + lg * 16) ^ ((lr & 7) << 4)));
          } else {
            const int pid = e >> 8;
            af[p] = *(const s16x8*)(outs + (size_t)pid * NODE_ELEMS +
                     (size_t)(row0 + lr) * DIM + ks * 32 + lg * 8);
          }
        }
        if (ks == 0) {
          // --- prefetch batch 2: W fragments for ks 2..3, before any MFMA ---
#pragma unroll
          for (int k2 = 2; k2 < 4; ++k2)
#pragma unroll
            for (int n = 0; n < 4; ++n)
              wf[k2][n] = *(const s16x8*)(Wp +
                  ((((size_t)node * 4 + k2) * 8 + h * 4 + n) << 9) + lane * 8);
        }
#pragma unroll
        for (int n = 0; n < 4; ++n)
#pragma unroll
          for (int p = 0; p < NDEG; ++p)
            acc[n] = __builtin_amdgcn_mfma_f32_16x16x32_bf16(af[p], wf[ks][n], acc[n], 0, 0, 0);
      }

      // epilogue
#pragma unroll
      for (int n = 0; n < 4; ++n) {
        const int col = (h * 4 + n) * 16 + lr;
        if (dv >= 0) {
          char* db = lds + (size_t)dv * TILE_B;
#pragma unroll
          for (int j = 0; j < 4; ++j) {
            const int row = lg * 4 + j;
            float v = fmaxf(acc[n][j] + bv[n], 0.f);
            *(uint16_t*)(db + ((row * 256 + col * 2) ^ ((row & 7) << 4))) = (uint16_t)f2bf(v);
          }
        } else if (dv == -1) {
          uint16_t* gb = outs + (size_t)node * NODE_ELEMS + (size_t)row0 * DIM + col;
#pragma unroll
          for (int j = 0; j < 4; ++j) {
            const int row = lg * 4 + j;
            float v = fmaxf(acc[n][j] + bv[n], 0.f);
            gb[(size_t)row * DIM] = (uint16_t)f2bf(v);
          }
        } else {  // -2: accumulate into f32 mean buffer
#pragma unroll
          for (int j = 0; j < 4; ++j) {
            const int row = lg * 4 + j;
            float v = fmaxf(acc[n][j] + bv[n], 0.f);
            atomicAdd(mb + row * DIM + col, v);
          }
        }
      }
    }
    __syncthreads();
  }

  // ---- mean store (f32), coalesced ----
  {
    const int r = t >> 7, c = t & 127;
    out[(size_t)(row0 + r) * DIM + c]     = mb[t] * 0.125f;
    out[(size_t)(row0 + 8 + r) * DIM + c] = mb[t + 1024] * 0.125f;
  }
}

// ---------------- host: replicate np.random.default_rng(0) graph ----------------
namespace nprng {
static inline uint32_t hashmix(uint32_t v, uint32_t& hc) {
  v ^= hc; hc *= 0x931e8875u; v *= hc; v ^= v >> 16; return v;
}
static inline uint32_t mixf(uint32_t x, uint32_t y) {
  uint32_t r = x * 0xca01f9ddu - y * 0x4973f715u;
  r ^= r >> 16;
  return r;
}
struct Pcg {
  unsigned __int128 state, inc;
  bool has32; uint32_t saved;
  void step() {
    const unsigned __int128 MUL =
        ((unsigned __int128)2549297995355413924ULL << 64) | 4865540595714422341ULL;
    state = state * MUL + inc;
  }
  void init_seed0() {
    uint32_t pool[4];
    uint32_t hc = 0x43b0d7e5u;
    for (int i = 0; i < 4; ++i) pool[i] = hashmix(0u, hc);
    for (int s = 0; s < 4; ++s)
      for (int d = 0; d < 4; ++d)
        if (s != d) pool[d] = mixf(pool[d], hashmix(pool[s], hc));
    uint32_t st[8];
    uint32_t hb = 0x8b51f9ddu;
    int cyc = 0;
    for (int i = 0; i < 8; ++i) {
      uint32_t dv = pool[cyc]; cyc = (cyc + 1) & 3;
      dv ^= hb; hb *= 0x58f38dedu; dv *= hb; dv ^= dv >> 16;
      st[i] = dv;
    }
    uint64_t v[4];
    for (int i = 0; i < 4; ++i)
      v[i] = (uint64_t)st[2 * i] | ((uint64_t)st[2 * i + 1] << 32);
    unsigned __int128 s128 = ((unsigned __int128)v[0] << 64) | v[1];
    unsigned __int128 i128 = ((unsigned __int128)v[2] << 64) | v[3];
    state = 0; inc = (i128 << 1) | 1;
    step(); state += s128; step();
    has32 = false; saved = 0;
  }
  uint64_t next64() {
    step();
    uint64_t rot = (uint64_t)(state >> 122);
    uint64_t x = (uint64_t)(state >> 64) ^ (uint64_t)state;
    return rot ? ((x >> rot) | (x << (64 - rot))) : x;
  }
  uint32_t next32() {
    if (has32) { has32 = false; return saved; }
    uint64_t v = next64();
    has32 = true; saved = (uint32_t)(v >> 32);
    return (uint32_t)v;
  }
  uint32_t lemire32(uint32_t rng_incl) {
    uint32_t rng_excl = rng_incl + 1u;
    uint64_t m = (uint64_t)next32() * (uint64_t)rng_excl;
    uint32_t leftover = (uint32_t)m;
    if (leftover < rng_excl) {
      uint32_t threshold = (0xFFFFFFFFu - rng_incl) % rng_excl;
      while (leftover < threshold) {
        m = (uint64_t)next32() * (uint64_t)rng_excl;
        leftover = (uint32_t)m;
      }
    }
    return (uint32_t)(m >> 32);
  }
};
}  // namespace nprng

extern "C" void kernel_launch(void* const* d_in, const int* in_sizes, int n_in,
                              void* d_out, int out_size, void* d_ws, size_t ws_size,
                              hipStream_t stream) {
  const float* X    = (const float*)d_in[0];
  const float* W    = (const float*)d_in[1];
  const float* bias = (const float*)d_in[2];
  float* out        = (float*)d_out;

  uint16_t* Wp   = (uint16_t*)d_ws;                                  // 2.13 MB packed W
  uint16_t* outs = (uint16_t*)((char*)d_ws + (size_t)NNODES * DIM * DIM * 2);  // spill space

  // ---- rebuild deterministic graph ----
  nprng::Pcg rng; rng.init_seed0();
  LayerSrcs srcs[NLAYERS];
  int n_prev = 1;
  for (int l = 0; l < NLAYERS; ++l) {
    for (int k = 0; k < KNODES; ++k)
      for (int j = 0; j < NDEG; ++j)
        srcs[l].p[k][j] = (n_prev == 1) ? 0 : (int)rng.lemire32((uint32_t)(n_prev - 1));
    n_prev += KNODES;
  }

  // ---- liveness: alive = contributes to the final mean ----
  bool alive[NNODES];
  for (int i = 0; i < NNODES; ++i) alive[i] = false;
  for (int i = NNODES - KNODES; i < NNODES; ++i) alive[i] = true;
  for (int l = NLAYERS - 1; l >= 0; --l)
    for (int k = 0; k < KNODES; ++k)
      if (alive[1 + l * KNODES + k])
        for (int j = 0; j < NDEG; ++j) alive[srcs[l].p[k][j]] = true;

  int last_use[NNODES];
  for (int i = 0; i < NNODES; ++i) last_use[i] = -1;
  for (int l = 0; l < NLAYERS; ++l)
    for (int k = 0; k < KNODES; ++k)
      if (alive[1 + l * KNODES + k])
        for (int j = 0; j < NDEG; ++j) {
          int s = srcs[l].p[k][j];
          if (l > last_use[s]) last_use[s] = l;
        }

  // ---- slot allocation (greedy, exact graph) ----
  int slot_of[NNODES];
  for (int i = 0; i < NNODES; ++i) slot_of[i] = -1;
  int freeStk[SLOTS], nfree = 0;
  for (int i = SLOTS - 1; i >= 0; --i) freeStk[nfree++] = i;

  Sched sch;
  slot_of[0] = freeStk[--nfree];           // node 0 always alive & first
  sch.root_dst = (int8_t)slot_of[0];

  for (int l = 0; l < NLAYERS; ++l) {
    for (int k = 0; k < KNODES; ++k) {
      const int node = 1 + l * KNODES + k;
      int dv;
      if (!alive[node])            dv = -3;
      else if (l == NLAYERS - 1)   dv = -2;                 // mean-only, LDS f32 accum
      else if (nfree > 0)          dv = slot_of[node] = freeStk[--nfree];
      else                         dv = -1;                 // global spill
      sch.dst[l * KNODES + k] = (int8_t)dv;

      uint64_t w64 = 0;
      for (int j = 0; j < NDEG; ++j) {
        const int src = srcs[l].p[k][j];
        const int enc = ((slot_of[src] + 1) & 0xff) | (src << 8);
        w64 |= (uint64_t)enc << (j * 16);
      }
      sch.pinfo[l * KNODES + k] = w64;
    }
    // free slots whose last use was this layer (reusable from layer l+1 on)
    for (int n = 0; n < NNODES; ++n)
      if (slot_of[n] >= 0 && last_use[n] == l) {
        freeStk[nfree++] = slot_of[n];
        slot_of[n] = -1;
      }
  }

  // ---- launch: 2 kernels total ----
  pack_w<<<dim3(520), dim3(256), 0, stream>>>(W, Wp);
  dag_exec<<<dim3(BATCH / ROWS), dim3(NTHREADS), 0, stream>>>(X, Wp, bias, outs, out, sch);
}

// Round 8
// 122.986 us; speedup vs baseline: 1.0333x; 1.0333x over previous
//
#include <hip/hip_runtime.h>
#include <cstdint>
#include <cstring>

#define BATCH   4096
#define DIM     128
#define NLAYERS 8
#define KNODES  8
#define NDEG    4
#define NNODES  65
#define NODE_ELEMS (BATCH * DIM)   // 524288 elems
#define ROWS    16                  // rows per block tile
#define SLOTS   37                  // LDS-resident activation slots
#define TILE_B  (ROWS * 256)        // 4096 B per bf16 tile (16 rows x 128 cols)
#define NTHREADS 1024

typedef float    f32x4 __attribute__((ext_vector_type(4)));
typedef short    s16x8 __attribute__((ext_vector_type(8)));
typedef uint32_t u32x4 __attribute__((ext_vector_type(4)));

struct LayerSrcs { int p[KNODES][NDEG]; };

struct Sched {
  uint64_t pinfo[NLAYERS * KNODES];  // per node: 4 x {slot+1 (8b), src node id (8b)}
  int8_t   dst[NLAYERS * KNODES];    // >=0 LDS slot, -1 global spill, -2 mean-only, -3 dead
  int8_t   root_dst;
};

// ---------------- device helpers ----------------
__device__ __forceinline__ uint32_t f2bf(float f) {   // RNE round to bf16
  union { float f; uint32_t i; } x; x.f = f;
  return (x.i + 0x7fffu + ((x.i >> 16) & 1u)) >> 16;
}
__device__ __forceinline__ uint32_t pack2(float a, float b) {
  return f2bf(a) | (f2bf(b) << 16);
}

// ---------------- W pre-pack: f32 row-major -> bf16 MFMA-fragment-linear ----------------
// chunk ci = (node*4 + ks)*8 + panel; elem offset = ci*512 + lane*8.
// element e = W[node][col = panel*16 + (lane&15)][k = ks*32 + (lane>>4)*8 + e]
__global__ __launch_bounds__(256)
void pack_w(const float* __restrict__ W, uint16_t* __restrict__ Wp) {
  int gid  = blockIdx.x * 256 + threadIdx.x;     // 65*2048 = 133120 total
  int lane = gid & 63;
  int n    = (gid >> 6) & 7;
  int ks   = (gid >> 9) & 3;
  int node = gid >> 11;
  int col  = n * 16 + (lane & 15);
  int k0   = ks * 32 + (lane >> 4) * 8;
  const float* src = W + ((size_t)node * DIM + col) * DIM + k0;
  f32x4 v0 = *(const f32x4*)src;
  f32x4 v1 = *(const f32x4*)(src + 4);
  u32x4 pk;
  pk.x = pack2(v0.x, v0.y); pk.y = pack2(v0.z, v0.w);
  pk.z = pack2(v1.x, v1.y); pk.w = pack2(v1.z, v1.w);
  *(u32x4*)(Wp + (size_t)gid * 8) = pk;
}

// ---------------- the persistent DAG executor ----------------
// 1024 threads = 16 waves = 8 nodes x 2 col-halves. One barrier per layer.
// Parent sum folded into the MFMA accumulator.
// Rolling depth-2 W prefetch + depth-1 A prefetch (R5 spill post-mortem:
// bulk-16 prefetch exceeded the 64-VGPR target and spilled; this peaks ~116
// live VGPRs with __launch_bounds__(1024,4) granting 128).
__global__ __launch_bounds__(NTHREADS, 4)
void dag_exec(const float* __restrict__ X, const uint16_t* __restrict__ Wp,
              const float* __restrict__ bias, uint16_t* __restrict__ outs,
              float* __restrict__ out, Sched sch)
{
  __shared__ char lds[SLOTS * TILE_B + 2048 * 4];   // 37 slots + f32 mean buffer = 156 KB
  float* mb = (float*)(lds + (size_t)SLOTS * TILE_B);

  const int t    = threadIdx.x;
  const int lane = t & 63;
  const int wv   = t >> 6;
  const int lr   = lane & 15;
  const int lg   = lane >> 4;
  const int kn   = wv & 7;      // node within layer
  const int h    = wv >> 3;     // col half (64 cols)
  const int row0 = blockIdx.x * ROWS;

  mb[t] = 0.f;
  mb[t + 1024] = 0.f;

  // ---- root: node 0, A = bf16(X); 8 waves, one col-panel each ----
  if (wv < 8) {
    f32x4 acc = (f32x4){0.f, 0.f, 0.f, 0.f};
    s16x8 wf[4];
#pragma unroll
    for (int ks = 0; ks < 4; ++ks)
      wf[ks] = *(const s16x8*)(Wp + (((size_t)(0 * 4 + ks) * 8 + wv) << 9) + lane * 8);
#pragma unroll
    for (int ks = 0; ks < 4; ++ks) {
      const float* xp = X + (size_t)(row0 + lr) * DIM + ks * 32 + lg * 8;
      f32x4 v0 = *(const f32x4*)xp;
      f32x4 v1 = *(const f32x4*)(xp + 4);
      u32x4 pk;
      pk.x = pack2(v0.x, v0.y); pk.y = pack2(v0.z, v0.w);
      pk.z = pack2(v1.x, v1.y); pk.w = pack2(v1.z, v1.w);
      s16x8 af;
      __builtin_memcpy(&af, &pk, 16);
      acc = __builtin_amdgcn_mfma_f32_16x16x32_bf16(af, wf[ks], acc, 0, 0, 0);
    }
    char* db = lds + (size_t)sch.root_dst * TILE_B;
    const int col = wv * 16 + lr;
    const float bv = bias[col];
#pragma unroll
    for (int j = 0; j < 4; ++j) {
      const int row = lg * 4 + j;
      float v = fmaxf(acc[j] + bv, 0.f);
      *(uint16_t*)(db + ((row * 256 + col * 2) ^ ((row & 7) << 4))) = (uint16_t)f2bf(v);
    }
  }
  __syncthreads();

  // ---- 8 layers, one wave-task per (node, col-half), one barrier per layer ----
  for (int l = 0; l < NLAYERS; ++l) {
    const int idx  = l * KNODES + kn;
    const int node = 1 + idx;
    const int dv   = sch.dst[idx];
    const uint64_t pinfo = sch.pinfo[idx];

    if (dv != -3) {
      // per-parent resolved bases (wave-uniform decode, per-lane address)
      const char* pbase[NDEG];
      bool pglob[NDEG];
#pragma unroll
      for (int p = 0; p < NDEG; ++p) {
        const int e  = (int)((pinfo >> (p * 16)) & 0xffff);
        const int ps = (e & 0xff) - 1;
        if (ps >= 0) {
          pbase[p] = lds + (size_t)ps * TILE_B;
          pglob[p] = false;
        } else {
          const int pid = e >> 8;
          pbase[p] = (const char*)(outs + (size_t)pid * NODE_ELEMS +
                                   (size_t)(row0 + lr) * DIM + lg * 8);
          pglob[p] = true;
        }
      }
      const uint16_t* wbase = Wp + ((((size_t)node * 4) * 8 + h * 4) << 9) + lane * 8;

      s16x8 wf[4][4];
      s16x8 af[4][4];

      // prologue: wf ks=0,1 (8 global loads in flight), af ks=0, bias
#pragma unroll
      for (int n = 0; n < 4; ++n)
        wf[0][n] = *(const s16x8*)(wbase + (size_t)(0 * 8 + n) * 512);
#pragma unroll
      for (int n = 0; n < 4; ++n)
        wf[1][n] = *(const s16x8*)(wbase + (size_t)(1 * 8 + n) * 512);
#pragma unroll
      for (int p = 0; p < NDEG; ++p)
        af[0][p] = pglob[p]
          ? *(const s16x8*)(pbase[p] + 0 * 64)
          : *(const s16x8*)(pbase[p] + ((lr * 256 + 0 * 64 + lg * 16) ^ ((lr & 7) << 4)));
      float bv[4];
#pragma unroll
      for (int n = 0; n < 4; ++n)
        bv[n] = bias[(size_t)node * DIM + (h * 4 + n) * 16 + lr];

      f32x4 acc[4];
#pragma unroll
      for (int n = 0; n < 4; ++n) acc[n] = (f32x4){0.f, 0.f, 0.f, 0.f};

      // rolling pipeline: stage ks computes with wf[ks]/af[ks],
      // issues wf[ks+2] (global) and af[ks+1] (LDS) ahead.
#pragma unroll
      for (int ks = 0; ks < 4; ++ks) {
        if (ks + 2 < 4) {
#pragma unroll
          for (int n = 0; n < 4; ++n)
            wf[ks + 2][n] = *(const s16x8*)(wbase + (size_t)((ks + 2) * 8 + n) * 512);
        }
        if (ks + 1 < 4) {
#pragma unroll
          for (int p = 0; p < NDEG; ++p)
            af[ks + 1][p] = pglob[p]
              ? *(const s16x8*)(pbase[p] + (ks + 1) * 64)
              : *(const s16x8*)(pbase[p] +
                  ((lr * 256 + (ks + 1) * 64 + lg * 16) ^ ((lr & 7) << 4)));
        }
#pragma unroll
        for (int n = 0; n < 4; ++n)
#pragma unroll
          for (int p = 0; p < NDEG; ++p)
            acc[n] = __builtin_amdgcn_mfma_f32_16x16x32_bf16(af[ks][p], wf[ks][n], acc[n], 0, 0, 0);
      }

      // epilogue
#pragma unroll
      for (int n = 0; n < 4; ++n) {
        const int col = (h * 4 + n) * 16 + lr;
        if (dv >= 0) {
          char* db = lds + (size_t)dv * TILE_B;
#pragma unroll
          for (int j = 0; j < 4; ++j) {
            const int row = lg * 4 + j;
            float v = fmaxf(acc[n][j] + bv[n], 0.f);
            *(uint16_t*)(db + ((row * 256 + col * 2) ^ ((row & 7) << 4))) = (uint16_t)f2bf(v);
          }
        } else if (dv == -1) {
          uint16_t* gb = outs + (size_t)node * NODE_ELEMS + (size_t)row0 * DIM + col;
#pragma unroll
          for (int j = 0; j < 4; ++j) {
            const int row = lg * 4 + j;
            float v = fmaxf(acc[n][j] + bv[n], 0.f);
            gb[(size_t)row * DIM] = (uint16_t)f2bf(v);
          }
        } else {  // -2: accumulate into f32 mean buffer
#pragma unroll
          for (int j = 0; j < 4; ++j) {
            const int row = lg * 4 + j;
            float v = fmaxf(acc[n][j] + bv[n], 0.f);
            atomicAdd(mb + row * DIM + col, v);
          }
        }
      }
    }
    __syncthreads();
  }

  // ---- mean store (f32), coalesced ----
  {
    const int r = t >> 7, c = t & 127;
    out[(size_t)(row0 + r) * DIM + c]     = mb[t] * 0.125f;
    out[(size_t)(row0 + 8 + r) * DIM + c] = mb[t + 1024] * 0.125f;
  }
}

// ---------------- host: replicate np.random.default_rng(0) graph ----------------
namespace nprng {
static inline uint32_t hashmix(uint32_t v, uint32_t& hc) {
  v ^= hc; hc *= 0x931e8875u; v *= hc; v ^= v >> 16; return v;
}
static inline uint32_t mixf(uint32_t x, uint32_t y) {
  uint32_t r = x * 0xca01f9ddu - y * 0x4973f715u;
  r ^= r >> 16;
  return r;
}
struct Pcg {
  unsigned __int128 state, inc;
  bool has32; uint32_t saved;
  void step() {
    const unsigned __int128 MUL =
        ((unsigned __int128)2549297995355413924ULL << 64) | 4865540595714422341ULL;
    state = state * MUL + inc;
  }
  void init_seed0() {
    uint32_t pool[4];
    uint32_t hc = 0x43b0d7e5u;
    for (int i = 0; i < 4; ++i) pool[i] = hashmix(0u, hc);
    for (int s = 0; s < 4; ++s)
      for (int d = 0; d < 4; ++d)
        if (s != d) pool[d] = mixf(pool[d], hashmix(pool[s], hc));
    uint32_t st[8];
    uint32_t hb = 0x8b51f9ddu;
    int cyc = 0;
    for (int i = 0; i < 8; ++i) {
      uint32_t dv = pool[cyc]; cyc = (cyc + 1) & 3;
      dv ^= hb; hb *= 0x58f38dedu; dv *= hb; dv ^= dv >> 16;
      st[i] = dv;
    }
    uint64_t v[4];
    for (int i = 0; i < 4; ++i)
      v[i] = (uint64_t)st[2 * i] | ((uint64_t)st[2 * i + 1] << 32);
    unsigned __int128 s128 = ((unsigned __int128)v[0] << 64) | v[1];
    unsigned __int128 i128 = ((unsigned __int128)v[2] << 64) | v[3];
    state = 0; inc = (i128 << 1) | 1;
    step(); state += s128; step();
    has32 = false; saved = 0;
  }
  uint64_t next64() {
    step();
    uint64_t rot = (uint64_t)(state >> 122);
    uint64_t x = (uint64_t)(state >> 64) ^ (uint64_t)state;
    return rot ? ((x >> rot) | (x << (64 - rot))) : x;
  }
  uint32_t next32() {
    if (has32) { has32 = false; return saved; }
    uint64_t v = next64();
    has32 = true; saved = (uint32_t)(v >> 32);
    return (uint32_t)v;
  }
  uint32_t lemire32(uint32_t rng_incl) {
    uint32_t rng_excl = rng_incl + 1u;
    uint64_t m = (uint64_t)next32() * (uint64_t)rng_excl;
    uint32_t leftover = (uint32_t)m;
    if (leftover < rng_excl) {
      uint32_t threshold = (0xFFFFFFFFu - rng_incl) % rng_excl;
      while (leftover < threshold) {
        m = (uint64_t)next32() * (uint64_t)rng_excl;
        leftover = (uint32_t)m;
      }
    }
    return (uint32_t)(m >> 32);
  }
};
}  // namespace nprng

extern "C" void kernel_launch(void* const* d_in, const int* in_sizes, int n_in,
                              void* d_out, int out_size, void* d_ws, size_t ws_size,
                              hipStream_t stream) {
  const float* X    = (const float*)d_in[0];
  const float* W    = (const float*)d_in[1];
  const float* bias = (const float*)d_in[2];
  float* out        = (float*)d_out;

  uint16_t* Wp   = (uint16_t*)d_ws;                                  // 2.13 MB packed W
  uint16_t* outs = (uint16_t*)((char*)d_ws + (size_t)NNODES * DIM * DIM * 2);  // spill space

  // ---- rebuild deterministic graph ----
  nprng::Pcg rng; rng.init_seed0();
  LayerSrcs srcs[NLAYERS];
  int n_prev = 1;
  for (int l = 0; l < NLAYERS; ++l) {
    for (int k = 0; k < KNODES; ++k)
      for (int j = 0; j < NDEG; ++j)
        srcs[l].p[k][j] = (n_prev == 1) ? 0 : (int)rng.lemire32((uint32_t)(n_prev - 1));
    n_prev += KNODES;
  }

  // ---- liveness: alive = contributes to the final mean ----
  bool alive[NNODES];
  for (int i = 0; i < NNODES; ++i) alive[i] = false;
  for (int i = NNODES - KNODES; i < NNODES; ++i) alive[i] = true;
  for (int l = NLAYERS - 1; l >= 0; --l)
    for (int k = 0; k < KNODES; ++k)
      if (alive[1 + l * KNODES + k])
        for (int j = 0; j < NDEG; ++j) alive[srcs[l].p[k][j]] = true;

  int last_use[NNODES];
  for (int i = 0; i < NNODES; ++i) last_use[i] = -1;
  for (int l = 0; l < NLAYERS; ++l)
    for (int k = 0; k < KNODES; ++k)
      if (alive[1 + l * KNODES + k])
        for (int j = 0; j < NDEG; ++j) {
          int s = srcs[l].p[k][j];
          if (l > last_use[s]) last_use[s] = l;
        }

  // ---- slot allocation (greedy, exact graph) ----
  int slot_of[NNODES];
  for (int i = 0; i < NNODES; ++i) slot_of[i] = -1;
  int freeStk[SLOTS], nfree = 0;
  for (int i = SLOTS - 1; i >= 0; --i) freeStk[nfree++] = i;

  Sched sch;
  slot_of[0] = freeStk[--nfree];           // node 0 always alive & first
  sch.root_dst = (int8_t)slot_of[0];

  for (int l = 0; l < NLAYERS; ++l) {
    for (int k = 0; k < KNODES; ++k) {
      const int node = 1 + l * KNODES + k;
      int dv;
      if (!alive[node])            dv = -3;
      else if (l == NLAYERS - 1)   dv = -2;                 // mean-only, LDS f32 accum
      else if (nfree > 0)          dv = slot_of[node] = freeStk[--nfree];
      else                         dv = -1;                 // global spill
      sch.dst[l * KNODES + k] = (int8_t)dv;

      uint64_t w64 = 0;
      for (int j = 0; j < NDEG; ++j) {
        const int src = srcs[l].p[k][j];
        const int enc = ((slot_of[src] + 1) & 0xff) | (src << 8);
        w64 |= (uint64_t)enc << (j * 16);
      }
      sch.pinfo[l * KNODES + k] = w64;
    }
    // free slots whose last use was this layer (reusable from layer l+1 on)
    for (int n = 0; n < NNODES; ++n)
      if (slot_of[n] >= 0 && last_use[n] == l) {
        freeStk[nfree++] = slot_of[n];
        slot_of[n] = -1;
      }
  }

  // ---- launch: 2 kernels total ----
  pack_w<<<dim3(520), dim3(256), 0, stream>>>(W, Wp);
  dag_exec<<<dim3(BATCH / ROWS), dim3(NTHREADS), 0, stream>>>(X, Wp, bias, outs, out, sch);
}